// Round 1
// baseline (261.757 us; speedup 1.0000x reference)
//
#include <hip/hip_runtime.h>
#include <math.h>

#define BB 1024
#define NN 1024
#define DD 64
#define MARGIN_V 0.5f
#define EPS_V 1e-6f

// ---------------------------------------------------------------------------
// Kernel 1: one block per batch row b.
//   - 256 threads = 4 waves; each wave processes 4 columns/iter.
//   - lane layout: group g = lane>>4 (column within quad), gl = lane&15
//     loads float4 at d = gl*4 -> one wave load = 1KB contiguous (4 columns).
//   - 16-lane-group shfl_xor reduce for the two squared sums.
//   - group leaders track loss partial + argmax(valid dist_neg) w/ first-index
//     tie-break, then 16-slot LDS reduce.
// ---------------------------------------------------------------------------
__global__ __launch_bounds__(256) void k_dist(const float* __restrict__ a,
                                              const float* __restrict__ p,
                                              const float* __restrict__ g,
                                              float* __restrict__ ws_loss,
                                              int* __restrict__ ws_sel,
                                              float* __restrict__ out_hasvalid)
{
    const int b    = blockIdx.x;
    const int tid  = threadIdx.x;
    const int lane = tid & 63;
    const int wave = tid >> 6;     // 0..3
    const int grp  = lane >> 4;    // 0..3 (column within the wave's quad)
    const int gl   = lane & 15;    // lane within 16-lane group

    const size_t base = (size_t)b * NN * DD;

    float loss_acc   = 0.f;
    float best_score = -INFINITY;
    int   best_idx   = 0;          // all-invalid rows must resolve to 0 (argmax of all -inf)
    int   any_valid  = 0;

    for (int i = 0; i < NN / 16; ++i) {
        const int n = i * 16 + wave * 4 + grp;
        const size_t off = base + (size_t)n * DD + (size_t)gl * 4;
        const float4 va = *(const float4*)(a + off);
        const float4 vp = *(const float4*)(p + off);
        const float4 vg = *(const float4*)(g + off);

        float dp = 0.f, dn = 0.f, t;
        t = va.x - vp.x + EPS_V; dp += t * t;
        t = va.y - vp.y + EPS_V; dp += t * t;
        t = va.z - vp.z + EPS_V; dp += t * t;
        t = va.w - vp.w + EPS_V; dp += t * t;
        t = va.x - vg.x + EPS_V; dn += t * t;
        t = va.y - vg.y + EPS_V; dn += t * t;
        t = va.z - vg.z + EPS_V; dn += t * t;
        t = va.w - vg.w + EPS_V; dn += t * t;

        // reduce across the 16-lane group (xor masks stay within the group)
        for (int m = 1; m < 16; m <<= 1) {
            dp += __shfl_xor(dp, m, 64);
            dn += __shfl_xor(dn, m, 64);
        }

        if (gl == 0) {
            const float dist_pos = sqrtf(dp);
            const float dist_neg = sqrtf(dn);
            const float diff = MARGIN_V + dist_pos - dist_neg;
            loss_acc += fmaxf(diff, 0.f);
            const bool valid = diff > 0.f;
            any_valid |= (int)valid;
            const float score = valid ? dist_neg : -INFINITY;
            // per-lane columns visited in increasing n -> strict > keeps first max
            if (score > best_score) { best_score = score; best_idx = n; }
        }
    }

    __shared__ float s_score[16];
    __shared__ int   s_idx[16];
    __shared__ float s_loss[16];
    __shared__ int   s_valid[16];
    if (gl == 0) {
        const int slot = wave * 4 + grp;
        s_score[slot] = best_score;
        s_idx[slot]   = best_idx;
        s_loss[slot]  = loss_acc;
        s_valid[slot] = any_valid;
    }
    __syncthreads();
    if (tid == 0) {
        float bs = s_score[0]; int bi = s_idx[0];
        float ls = s_loss[0];  int av = s_valid[0];
        for (int k = 1; k < 16; ++k) {
            const float sc = s_score[k]; const int ix = s_idx[k];
            if (sc > bs || (sc == bs && ix < bi)) { bs = sc; bi = ix; }
            ls += s_loss[k];
            av |= s_valid[k];
        }
        ws_loss[b] = ls;
        ws_sel[b]  = bi;
        out_hasvalid[b] = av ? 1.0f : 0.0f;
    }
}

// ---------------------------------------------------------------------------
// Kernel 2: reduce the 1024 per-block loss partials -> out[0] = mean.
// ---------------------------------------------------------------------------
__global__ __launch_bounds__(1024) void k_loss(const float* __restrict__ ws_loss,
                                               float* __restrict__ out_loss)
{
    __shared__ float s[16];
    const int t = threadIdx.x;
    float v = ws_loss[t];
    for (int m = 1; m < 64; m <<= 1) v += __shfl_xor(v, m, 64);
    if ((t & 63) == 0) s[t >> 6] = v;
    __syncthreads();
    if (t == 0) {
        float tot = 0.f;
        for (int k = 0; k < 16; ++k) tot += s[k];
        out_loss[0] = tot / (float)((size_t)BB * NN);
    }
}

// ---------------------------------------------------------------------------
// Kernel 3: hard_neg[b] = negative[sel_col[b]]  (N*D = 65536 floats per b).
// Dest (out+1) is 4B-misaligned vs 16B, so scalar float copies (still fully
// coalesced: 256B per wave store instruction).
// ---------------------------------------------------------------------------
__global__ __launch_bounds__(256) void k_gather(const float* __restrict__ g,
                                                const int* __restrict__ ws_sel,
                                                float* __restrict__ out_hn)
{
    const int b   = blockIdx.y;
    const int sel = ws_sel[b];
    const float* __restrict__ src = g      + (size_t)sel * (NN * DD);
    float* __restrict__       dst = out_hn + (size_t)b   * (NN * DD);
    const int t = blockIdx.x * blockDim.x + threadIdx.x;   // 0..8191
    #pragma unroll
    for (int k = 0; k < (NN * DD) / 8192; ++k) {
        const int idx = t + k * 8192;
        dst[idx] = src[idx];
    }
}

extern "C" void kernel_launch(void* const* d_in, const int* in_sizes, int n_in,
                              void* d_out, int out_size, void* d_ws, size_t ws_size,
                              hipStream_t stream) {
    const float* anchor   = (const float*)d_in[0];
    const float* positive = (const float*)d_in[1];
    const float* negative = (const float*)d_in[2];
    float* out = (float*)d_out;

    // out layout: [0] loss | [1 .. 1+B*N*D) hard_neg | [1+B*N*D .. +B) has_valid
    float* out_loss     = out;
    float* out_hard_neg = out + 1;
    float* out_hasvalid = out + 1 + (size_t)BB * NN * DD;

    // ws layout: B floats (loss partials) + B ints (sel_col)  = 8 KB
    float* ws_loss = (float*)d_ws;
    int*   ws_sel  = (int*)((float*)d_ws + BB);

    k_dist<<<dim3(BB), dim3(256), 0, stream>>>(anchor, positive, negative,
                                               ws_loss, ws_sel, out_hasvalid);
    k_loss<<<dim3(1), dim3(1024), 0, stream>>>(ws_loss, out_loss);
    k_gather<<<dim3(32, BB), dim3(256), 0, stream>>>(negative, ws_sel, out_hard_neg);
}